// Round 6
// baseline (1567.450 us; speedup 1.0000x reference)
//
#include <hip/hip_runtime.h>
#include <hip/hip_bf16.h>
#include <stdint.h>

// Problem constants (fixed by reference)
#define BATCH 16
#define NPTS  8192
#define NCH   6
#define NGRP  512   // NUM_GROUPS (FPS samples)
#define GSZ   32    // GROUP_SIZE (kNN)

#define TPB     1024           // threads per block (both roles)
#define FPS_TPB 512            // fps: compute threads (8 waves)
#define FPS_PPT 16             // fps: contiguous mapping, idx = tid*16 + j
#define FPS_W   8              // fps: compute waves in the handshake
#define RING    32             // fps: slot ring depth (publisher decoupling)
#define GPB     4              // knn groups per block (4 x 256-thread subunits)
#define KNB     (BATCH * NGRP / GPB)  // 2048 knn blocks

typedef float v2f __attribute__((ext_vector_type(2)));
typedef float v4f __attribute__((ext_vector_type(4)));

// DPP ctrl encodings (gfx9+): row_shr:N = 0x110|N, row_bcast15/31 = 0x142/0x143
template <int CTRL>
__device__ __forceinline__ float dpp_max_f32(float v) {
  // bound_ctrl=1 -> invalid source lanes read 0; reduced values are squared
  // distances >= 0, so max-with-0 is identity-safe. (validated r7-r17)
  const int t =
      __builtin_amdgcn_update_dpp(0, __float_as_int(v), CTRL, 0xf, 0xf, true);
  return fmaxf(v, __int_as_float(t));
}

template <int CTRL>
__device__ __forceinline__ unsigned dpp_min_u32(unsigned v) {
  // bound_ctrl=0 + old=0xFFFFFFFF -> invalid lanes yield the min identity.
  // (validated r10-r17)
  const int t = __builtin_amdgcn_update_dpp((int)0xFFFFFFFF, (int)v, CTRL,
                                            0xf, 0xf, false);
  const unsigned tu = (unsigned)t;
  return v < tu ? v : tu;
}

// ws layout (uints): [0] ticket counter; [32 + b*32] progress[b]
//
// ---------------------------------------------------------------------------
// ROUND-26: congestion cuts on the r21 base (knn role VERBATIM r17).
// Evidence synthesis r20/r21/r25: ISSUE/pipe-occupancy cuts convert ~1:1 to
// wall time; pure latency-chain cuts convert to ~0 => critical path is
// congestion-like. Two unmodeled shared-pipe consumers:
//   (a) the speculative ALL-LANE cache[idxbest] gather: 64 lanes x random
//       16B x 8 waves of bank-conflicted LDS-pipe time per iteration, for a
//       value only 1 lane (the owner) uses;
//   (b) the publisher wave HOT-SPINNING on SIMD0, stealing issue slots from
//       the 2 compute waves sharing that SIMD -> they straggle, gating every
//       handshake.
// Changes vs r21 (r25's fused poll REVERTED to r21's two-phase handshake):
//   * register-select owner coords: carry (cnd,x,y,z) through the min-tree
//     via cndmask; DELETE the LDS gather. FPS inner loop is now LDS-free
//     except the slot handshake. Bit-identical: px/py/pz hold the same bits
//     cache held (loaded from it), and the tree picks the same cmin
//     (.x-over-.y / low-m priority; real candidates unique, INF ties moot).
//   * publisher sleep-poll: s_sleep(4) between failed polls parks the wave
//     (zero issue contention); <=256-cyc added lag vs 31-iter ring horizon.
// Numerics (bit-exact r2/r4/r7+ lineage): d=(dx*dx+dy*dy)+dz*dz, contract
// off, elementwise min; argmax-first == value max -> min index (ctz min
// lane, ctz min slot, contiguous mapping). Publisher-wave protocol (r21)
// unchanged; cross-XCD protocol (r5/r8/r15 lineage) unchanged.
// Pre-commit: dur <= 620 confirms congestion theory; >= 645 falsifies both
// sub-theories -> residual is clock/irreducible; next = 4-wave variant.
// ---------------------------------------------------------------------------
__global__ __launch_bounds__(TPB, 1) void fused_kernel(
    const float* __restrict__ points, float* __restrict__ grouped,
    float* __restrict__ centers, unsigned* __restrict__ ws) {
#pragma clang fp contract(off)
  __shared__ __align__(16) union {
    struct {  // fps role
      float cache[NPTS * 4];           // xyz pad-to-16B per point, 128 KiB
      float wdata[RING][FPS_W][4];     // slot {val, x, y, z}
      unsigned wtag[RING][FPS_W];      // slot sequence tags
    } f;
    struct {  // knn role
      unsigned long long wtop[16][GSZ];      // per-wave top-32 candidates
      int knn_sh[GPB][GSZ];
    } k;
  } u;
  __shared__ unsigned ticket_sh;

  const int tid  = threadIdx.x;
  const int lane = tid & 63;
  const int wave = tid >> 6;

  if (tid == 0) ticket_sh = atomicAdd(ws, 1u);
  __syncthreads();
  const unsigned ticket = ticket_sh;

  if (ticket < BATCH) {
    // ========== FPS role: one block per batch ==========
    const int b = (int)ticket;
    const float* P = points + (size_t)b * NPTS * NCH;
    float* C = centers + (size_t)b * NGRP * 3;
    unsigned* prog = ws + 32 + b * 32;

    // cooperative cache fill: all 1024 threads, 8 points each, b128 stores
#pragma unroll
    for (int j = 0; j < 8; ++j) {
      const int i = tid * 8 + j;
      const float2 xy = *reinterpret_cast<const float2*>(P + (size_t)i * 6);
      const float z = P[i * 6 + 2];
      v4f c4;
      c4.x = xy.x; c4.y = xy.y; c4.z = z; c4.w = 0.0f;
      *reinterpret_cast<v4f*>(&u.f.cache[i * 4]) = c4;
    }
    if (tid < RING * FPS_W) u.f.wtag[tid >> 3][tid & 7] = 0;  // tags below any k
    __syncthreads();  // cache + tag init ready (all 16 waves present)

    if (wave == FPS_W) {
      // ===== publisher wave: consumes the slot ring, owns C + prog =====
      if (lane == 0) {  // C[0] = start point (index 0, reference semantics)
        C[0] = u.f.cache[0];
        C[1] = u.f.cache[1];
        C[2] = u.f.cache[2];
      }
      for (int k = 1; k < NGRP; ++k) {
        // publish BEFORE storing C[k]: at this point C[0..k-1] are issued in
        // program order -> the release (waitcnt + wbl2) covers exactly them.
        if ((k & 7) == 0 && lane == 0)
          __hip_atomic_store(prog, (unsigned)k, __ATOMIC_RELEASE,
                             __HIP_MEMORY_SCOPE_AGENT);
        const int p = k & (RING - 1);
        // sleep-poll: parked wave issues nothing -> no SIMD0 contention
        for (;;) {
          const unsigned tg =
              __hip_atomic_load(&u.f.wtag[p][lane & 7], __ATOMIC_ACQUIRE,
                                __HIP_MEMORY_SCOPE_WORKGROUP);
          if (__ballot(tg == (unsigned)k) == ~0ull) break;
          __builtin_amdgcn_s_sleep(4);
        }

        const v4f sl =
            *reinterpret_cast<const v4f*>(&u.f.wdata[p][lane & 7][0]);
        float r = sl.x;
        r = dpp_max_f32<0x111>(r); r = dpp_max_f32<0x112>(r);
        r = dpp_max_f32<0x114>(r);
        const float gmax =
            __int_as_float(__builtin_amdgcn_readlane(__float_as_int(r), 7));
        const int sstar =
            (int)__builtin_ctzll(__ballot(sl.x == gmax) & 0xFFull);
        const float lx =
            __int_as_float(__builtin_amdgcn_readlane(__float_as_int(sl.y), sstar));
        const float ly =
            __int_as_float(__builtin_amdgcn_readlane(__float_as_int(sl.z), sstar));
        const float lz =
            __int_as_float(__builtin_amdgcn_readlane(__float_as_int(sl.w), sstar));
        if (lane == 0) {
          C[k * 3 + 0] = lx;
          C[k * 3 + 1] = ly;
          C[k * 3 + 2] = lz;
        }
      }
      if (lane == 0)  // final full publish (release drains all C stores)
        __hip_atomic_store(prog, (unsigned)NGRP, __ATOMIC_RELEASE,
                           __HIP_MEMORY_SCOPE_AGENT);
      return;
    }
    if (tid >= FPS_TPB) return;  // waves 9..15 retire; no barriers after this

    // register preload from LDS cache: 16 contiguous points per thread
    v2f px[8], py[8], pz[8], md[8];
#pragma unroll
    for (int m = 0; m < 8; ++m) {
      const v4f a =
          *reinterpret_cast<const v4f*>(&u.f.cache[(tid * FPS_PPT + 2 * m) * 4]);
      const v4f bb = *reinterpret_cast<const v4f*>(
          &u.f.cache[(tid * FPS_PPT + 2 * m + 1) * 4]);
      px[m] = (v2f){a.x, bb.x};
      py[m] = (v2f){a.y, bb.y};
      pz[m] = (v2f){a.z, bb.z};
      md[m] = (v2f){__builtin_inff(), __builtin_inff()};
    }
    float lx, ly, lz;
    {
      const v4f c0 = *reinterpret_cast<const v4f*>(&u.f.cache[0]);
      lx = c0.x; ly = c0.y; lz = c0.z;  // start index 0 (reference)
    }

    for (int k = 1; k < NGRP; ++k) {
      // ---- inner: packed min-dist update ----
      const v2f vlx = {lx, lx}, vly = {ly, ly}, vlz = {lz, lz};
#pragma unroll
      for (int m = 0; m < 8; ++m) {
        const v2f dx = px[m] - vlx;
        const v2f dy = py[m] - vly;
        const v2f dz = pz[m] - vlz;
        const v2f d  = (dx * dx + dy * dy) + dz * dz;  // ref op order, no fma
        md[m] = __builtin_elementwise_min(md[m], d);
      }
      // pairwise max tree (same value set; fmax returns one of its inputs ->
      // bestv bits independent of association order)
      const v2f t01 = __builtin_elementwise_max(md[0], md[1]);
      const v2f t23 = __builtin_elementwise_max(md[2], md[3]);
      const v2f t45 = __builtin_elementwise_max(md[4], md[5]);
      const v2f t67 = __builtin_elementwise_max(md[6], md[7]);
      const v2f t03 = __builtin_elementwise_max(t01, t23);
      const v2f t47 = __builtin_elementwise_max(t45, t67);
      const v2f b2  = __builtin_elementwise_max(t03, t47);
      const float bestv = fmaxf(b2.x, b2.y);

      // ---- candidate (idx,x,y,z) payload min-tree, all in registers ----
      // leaf: .x (2m) overrides .y (2m+1); losers get INF idx (coords moot).
      unsigned cnd[8]; float ccx[8], ccy[8], ccz[8];
#pragma unroll
      for (int m = 0; m < 8; ++m) {
        const bool sx = (md[m].x == bestv);
        const bool sy = (md[m].y == bestv);
        cnd[m] = sx ? (unsigned)(2 * m)
                    : (sy ? (unsigned)(2 * m + 1) : 0xFFFFFFFFu);
        ccx[m] = sx ? px[m].x : px[m].y;
        ccy[m] = sx ? py[m].x : py[m].y;
        ccz[m] = sx ? pz[m].x : pz[m].y;
      }
      // tree: min cnd wins (strict < keeps lower-m on INF ties; real
      // candidate indices are unique so no real tie exists)
#define SEL2(o, a, b)                                                          \
  const bool w##o = (cnd[b] < cnd[a]);                                         \
  const unsigned n##o = w##o ? cnd[b] : cnd[a];                                \
  const float x##o = w##o ? ccx[b] : ccx[a];                                   \
  const float y##o = w##o ? ccy[b] : ccy[a];                                   \
  const float z##o = w##o ? ccz[b] : ccz[a];
      SEL2(A, 0, 1) SEL2(B, 2, 3) SEL2(C, 4, 5) SEL2(D, 6, 7)
#undef SEL2
#define SEL2N(o, a, b)                                                         \
  const bool w##o = (n##b < n##a);                                             \
  const unsigned n##o = w##o ? n##b : n##a;                                    \
  const float x##o = w##o ? x##b : x##a;                                       \
  const float y##o = w##o ? y##b : y##a;                                       \
  const float z##o = w##o ? z##b : z##a;
      SEL2N(E, A, B) SEL2N(F, C, D) SEL2N(G, E, F)
#undef SEL2N
      // winner of this thread: index tid*16 + nG, coords (xG,yG,zG)

      // ---- level-1: wave max via DPP (VALU only) ----
      float wv = bestv;
      wv = dpp_max_f32<0x111>(wv); wv = dpp_max_f32<0x112>(wv);
      wv = dpp_max_f32<0x114>(wv); wv = dpp_max_f32<0x118>(wv);
      wv = dpp_max_f32<0x142>(wv); wv = dpp_max_f32<0x143>(wv);
      const float wvmax =
          __int_as_float(__builtin_amdgcn_readlane(__float_as_int(wv), 63));
      const int owner = (int)__builtin_ctzll(__ballot(bestv == wvmax));

      const int p = k & (RING - 1);
      if (lane == owner) {
        v4f s;
        s.x = wvmax; s.y = xG; s.z = yG; s.w = zG;
        *reinterpret_cast<v4f*>(&u.f.wdata[p][wave][0]) = s;  // one b128
        __hip_atomic_store(&u.f.wtag[p][wave], (unsigned)k, __ATOMIC_RELEASE,
                           __HIP_MEMORY_SCOPE_WORKGROUP);
      }

      // ---- tag poll replaces __syncthreads (no vmcnt drain) ----
      unsigned tg;
      do {
        tg = __hip_atomic_load(&u.f.wtag[p][lane & 7], __ATOMIC_ACQUIRE,
                               __HIP_MEMORY_SCOPE_WORKGROUP);
      } while (__ballot(tg == (unsigned)k) != ~0ull);

      // ---- level-2: ONE b128 slot read, 3-step DPP, coord readlanes ----
      const v4f sl =
          *reinterpret_cast<const v4f*>(&u.f.wdata[p][lane & 7][0]);
      float r = sl.x;
      r = dpp_max_f32<0x111>(r); r = dpp_max_f32<0x112>(r);
      r = dpp_max_f32<0x114>(r);
      const float gmax =
          __int_as_float(__builtin_amdgcn_readlane(__float_as_int(r), 7));
      const int sstar =
          (int)__builtin_ctzll(__ballot(sl.x == gmax) & 0xFFull);
      lx = __int_as_float(__builtin_amdgcn_readlane(__float_as_int(sl.y), sstar));
      ly = __int_as_float(__builtin_amdgcn_readlane(__float_as_int(sl.z), sstar));
      lz = __int_as_float(__builtin_amdgcn_readlane(__float_as_int(sl.w), sstar));
    }
    // compute waves: nothing to finalize -- publisher owns C[511] + prog.
  } else {
    // ====== kNN role: 4 groups per block (tie-fast-path) ========
    const unsigned gid = ticket - BATCH;           // g-major ordering
    const int b  = (int)(gid & 15);
    const int g0 = (int)(gid >> 4) * GPB;
    const int sub  = tid >> 8;                     // subunit 0..3
    const int t256 = tid & 255;                    // tid within subunit
    const int g = g0 + sub;
    const float* P = points + (size_t)b * NPTS * NCH;
    const float* cen = centers + ((size_t)b * NGRP + g) * 3;
    unsigned* prog = ws + 32 + b * 32;

    if (tid == 0) {  // spin until all 4 centers are published
      while (__hip_atomic_load(prog, __ATOMIC_ACQUIRE,
                               __HIP_MEMORY_SCOPE_AGENT) <
             (unsigned)(g0 + GPB))
        __builtin_amdgcn_s_sleep(64);
    }
    __syncthreads();

    // center via agent-scope atomic loads (fresh across XCDs)
    const float cx = __hip_atomic_load(&cen[0], __ATOMIC_RELAXED,
                                       __HIP_MEMORY_SCOPE_AGENT);
    const float cy = __hip_atomic_load(&cen[1], __ATOMIC_RELAXED,
                                       __HIP_MEMORY_SCOPE_AGENT);
    const float cz = __hip_atomic_load(&cen[2], __ATOMIC_RELAXED,
                                       __HIP_MEMORY_SCOPE_AGENT);
    const float cc = (cx * cx + cy * cy) + cz * cz;

    unsigned long long keys[32];
#pragma unroll
    for (int j = 0; j < 32; ++j) {
      const int i = j * 256 + t256;
      const float2 xy = *reinterpret_cast<const float2*>(P + (size_t)i * 6);
      const float x = xy.x, y = xy.y;
      const float z = P[i * 6 + 2];
      const float xx  = (x * x + y * y) + z * z;
      const float dot = fmaf(cz, z, fmaf(cy, y, cx * x));  // einsum fma chain
      const float d2  = (cc - 2.0f * dot) + xx;
      unsigned uu = __float_as_uint(d2);
      uu = (uu & 0x80000000u) ? ~uu : (uu | 0x80000000u);  // sortable map
      keys[j] = ((unsigned long long)uu << 32) | (unsigned long long)(unsigned)i;
    }

    // 4 group mins (8 keys each) + overall min
    unsigned long long gm[4];
#pragma unroll
    for (int g2 = 0; g2 < 4; ++g2) {
      unsigned long long m = keys[g2 * 8];
#pragma unroll
      for (int t = 1; t < 8; ++t) {
        const unsigned long long o = keys[g2 * 8 + t];
        m = m < o ? m : o;
      }
      gm[g2] = m;
    }
    unsigned long long lmin;
    {
      const unsigned long long a2 = gm[0] < gm[1] ? gm[0] : gm[1];
      const unsigned long long b3 = gm[2] < gm[3] ? gm[2] : gm[3];
      lmin = a2 < b3 ? a2 : b3;
    }

    // ---- phase 1: per-wave top-32, NO barriers; tie-fast-path rounds ----
    for (int r2 = 0; r2 < GSZ; ++r2) {
      const unsigned vcur = (unsigned)(lmin >> 32);
      const unsigned icur = (unsigned)(lmin & 0xFFFFFFFFull);
      unsigned vm = vcur;
      vm = dpp_min_u32<0x111>(vm); vm = dpp_min_u32<0x112>(vm);
      vm = dpp_min_u32<0x114>(vm); vm = dpp_min_u32<0x118>(vm);
      vm = dpp_min_u32<0x142>(vm); vm = dpp_min_u32<0x143>(vm);
      const unsigned vmin = (unsigned)__builtin_amdgcn_readlane((int)vm, 63);

      // fast path: unique lane holds vmin -> its icur is the exact
      // (val,idx)-lexicographic min index. Fallback (bit-identical cross-
      // lane val tie, rare): full idx DPP chain, identical to r10-r16.
      const unsigned long long mask = __ballot(vcur == vmin);
      unsigned imin;
      if (__builtin_popcountll(mask) == 1) {  // wave-uniform branch
        imin = (unsigned)__builtin_amdgcn_readlane(
            (int)icur, (int)__builtin_ctzll(mask));
      } else {
        unsigned ic = (vcur == vmin) ? icur : 0xFFFFFFFFu;
        ic = dpp_min_u32<0x111>(ic); ic = dpp_min_u32<0x112>(ic);
        ic = dpp_min_u32<0x114>(ic); ic = dpp_min_u32<0x118>(ic);
        ic = dpp_min_u32<0x142>(ic); ic = dpp_min_u32<0x143>(ic);
        imin = (unsigned)__builtin_amdgcn_readlane((int)ic, 63);
      }
      const unsigned long long wk =
          ((unsigned long long)vmin << 32) | (unsigned long long)imin;

      if (lane == (int)(imin & 63u)) {  // owner removes winner
#pragma unroll
        for (int g2 = 0; g2 < 4; ++g2) {
          if (gm[g2] == wk) {
            unsigned long long m = ~0ull;
#pragma unroll
            for (int t = 0; t < 8; ++t) {
              const int s = g2 * 8 + t;
              if (keys[s] == wk) keys[s] = ~0ull;
              const unsigned long long o = keys[s];
              m = m < o ? m : o;
            }
            gm[g2] = m;
          }
        }
        const unsigned long long a2 = gm[0] < gm[1] ? gm[0] : gm[1];
        const unsigned long long b3 = gm[2] < gm[3] ? gm[2] : gm[3];
        lmin = a2 < b3 ? a2 : b3;
      }
      if (lane == 0) u.k.wtop[wave][r2] = wk;
    }
    __syncthreads();  // wtop ready

    // ---- phase 2: wave 4*sub bitonic-sorts its 128 candidates ----
    if ((wave & 3) == 0) {
      const unsigned long long* flat = &u.k.wtop[4 * sub][0];
      unsigned long long a = flat[lane];
      unsigned long long c = flat[lane + 64];
#pragma unroll
      for (int k2 = 2; k2 <= 128; k2 <<= 1) {
#pragma unroll
        for (int j2 = k2 >> 1; j2 >= 1; j2 >>= 1) {
          if (j2 == 64) {  // within-lane slot exchange (only at k2 == 128)
            const unsigned long long mn = a < c ? a : c;
            const unsigned long long mx = a < c ? c : a;
            a = mn; c = mx;
          } else {
            const bool upa = ((lane & k2) == 0);
            const bool upc = (((lane + 64) & k2) == 0);
            const unsigned long long oa = __shfl_xor(a, j2);
            const unsigned long long oc = __shfl_xor(c, j2);
            const bool low = ((lane & j2) == 0);
            const unsigned long long mna = a < oa ? a : oa;
            const unsigned long long mxa = a < oa ? oa : a;
            const unsigned long long mnc = c < oc ? c : oc;
            const unsigned long long mxc = c < oc ? oc : c;
            a = (low == upa) ? mna : mxa;
            c = (low == upc) ? mnc : mxc;
          }
        }
      }
      if (lane < GSZ) u.k.knn_sh[sub][lane] = (int)(unsigned)(a & 0xFFFFFFFFull);
    }
    __syncthreads();

    // gather + center-relative xyz; 192 output floats per group
    float* outg = grouped + ((size_t)b * NGRP + g) * GSZ * NCH;
    if (t256 < GSZ * NCH) {
      const int n = t256 / 6, c2 = t256 % 6;
      const int idx = u.k.knn_sh[sub][n];
      float v = P[idx * 6 + c2];
      if (c2 < 3) {
        const float cv = (c2 == 0) ? cx : (c2 == 1) ? cy : cz;
        v = v - cv;  // exact ref subtract
      }
      outg[t256] = v;
    }
  }
}

extern "C" void kernel_launch(void* const* d_in, const int* in_sizes, int n_in,
                              void* d_out, int out_size, void* d_ws, size_t ws_size,
                              hipStream_t stream) {
  const float* points = (const float*)d_in[0];
  float* out = (float*)d_out;
  float* grouped = out;                                        // [16,512,32,6]
  float* centers = out + (size_t)BATCH * NGRP * GSZ * NCH;     // [16,512,3]
  unsigned* ws = (unsigned*)d_ws;

  // zero ticket counter + progress flags (ws is poisoned 0xAA pre-launch)
  hipMemsetAsync(ws, 0, 4096, stream);
  fused_kernel<<<BATCH + KNB, TPB, 0, stream>>>(points, grouped, centers, ws);
}

// Round 7
// 644.489 us; speedup vs baseline: 2.4321x; 2.4321x over previous
//
#include <hip/hip_runtime.h>
#include <hip/hip_bf16.h>
#include <stdint.h>

// Problem constants (fixed by reference)
#define BATCH 16
#define NPTS  8192
#define NCH   6
#define NGRP  512   // NUM_GROUPS (FPS samples)
#define GSZ   32    // GROUP_SIZE (kNN)

#define TPB     1024           // threads per block (both roles)
#define FPS_TPB 512            // fps: compute threads (8 waves)
#define FPS_PPT 16             // fps: contiguous mapping, idx = tid*16 + j
#define FPS_W   8              // fps: compute waves in the handshake
#define RING    32             // fps: slot ring depth (publisher decoupling)
#define GPB     4              // knn groups per block (4 x 256-thread subunits)
#define KNB     (BATCH * NGRP / GPB)  // 2048 knn blocks

typedef float v2f __attribute__((ext_vector_type(2)));
typedef float v4f __attribute__((ext_vector_type(4)));

// DPP ctrl encodings (gfx9+): row_shr:N = 0x110|N, row_bcast15/31 = 0x142/0x143
template <int CTRL>
__device__ __forceinline__ float dpp_max_f32(float v) {
  // bound_ctrl=1 -> invalid source lanes read 0; reduced values are squared
  // distances >= 0, so max-with-0 is identity-safe. (validated r7-r17)
  const int t =
      __builtin_amdgcn_update_dpp(0, __float_as_int(v), CTRL, 0xf, 0xf, true);
  return fmaxf(v, __int_as_float(t));
}

template <int CTRL>
__device__ __forceinline__ unsigned dpp_min_u32(unsigned v) {
  // bound_ctrl=0 + old=0xFFFFFFFF -> invalid lanes yield the min identity.
  // (validated r10-r17)
  const int t = __builtin_amdgcn_update_dpp((int)0xFFFFFFFF, (int)v, CTRL,
                                            0xf, 0xf, false);
  const unsigned tu = (unsigned)t;
  return v < tu ? v : tu;
}

// ws layout (uints): [0] ticket counter; [32 + b*32] progress[b]
//
// ---------------------------------------------------------------------------
// ROUND-27 = r21 BYTE-EXACT (best measured: 653.5us) + ONE isolated change:
// publisher sleep-poll.
// Post-mortem r26: register-select tree (32 extra live temps through cndmask
// trees) crossed the register-allocation cliff -> scratch spills (FETCH/WRITE
// up, VALUBusy 26->12%, dur 1567us, one 42ms outlier). Reverted wholesale.
// Lesson: the FPS loop codegen is fragile -- only near-zero-register
// perturbations allowed. Sub-theory (a) (all-lane gather congestion) remains
// untested; sub-theory (b) (publisher hot-spin steals SIMD0 issue from
// compute waves 0/4 -- the handshake's structural stragglers) is what this
// round isolates.
// Change vs r21 (the ONLY change): publisher poll loop sleeps s_sleep(1)
// between failed tag reads. Sleep fires only when the publisher is CAUGHT UP
// (when behind, first read succeeds -> full speed ~560cyc/iter << tau), so
// ring lag stays << 31 -> no overwrite hazard, no deadlock, no register
// pressure, FPS compute loop untouched.
// Pre-commit: dur <= 655 keep; > 670 refutes (b) -> serialization floor
// reached or take the 4-wave big swing next.
// Numerics (bit-exact r2/r4/r7+ lineage): d=(dx*dx+dy*dy)+dz*dz, contract
// off, elementwise min; argmax-first == value max -> min index (idx-tree
// .x-over-.y / low-j priority, ctz min lane, ctz min slot, contiguous
// mapping). Publisher-wave protocol (r21) unchanged; cross-XCD protocol
// (r5/r8/r15 lineage) unchanged. knn role byte-for-byte r17.
// ---------------------------------------------------------------------------
__global__ __launch_bounds__(TPB, 1) void fused_kernel(
    const float* __restrict__ points, float* __restrict__ grouped,
    float* __restrict__ centers, unsigned* __restrict__ ws) {
#pragma clang fp contract(off)
  __shared__ __align__(16) union {
    struct {  // fps role
      float cache[NPTS * 4];           // xyz pad-to-16B per point, 128 KiB
      float wdata[RING][FPS_W][4];     // slot {val, x, y, z}
      unsigned wtag[RING][FPS_W];      // slot sequence tags
    } f;
    struct {  // knn role
      unsigned long long wtop[16][GSZ];      // per-wave top-32 candidates
      int knn_sh[GPB][GSZ];
    } k;
  } u;
  __shared__ unsigned ticket_sh;

  const int tid  = threadIdx.x;
  const int lane = tid & 63;
  const int wave = tid >> 6;

  if (tid == 0) ticket_sh = atomicAdd(ws, 1u);
  __syncthreads();
  const unsigned ticket = ticket_sh;

  if (ticket < BATCH) {
    // ========== FPS role: one block per batch ==========
    const int b = (int)ticket;
    const float* P = points + (size_t)b * NPTS * NCH;
    float* C = centers + (size_t)b * NGRP * 3;
    unsigned* prog = ws + 32 + b * 32;

    // cooperative cache fill: all 1024 threads, 8 points each, b128 stores
#pragma unroll
    for (int j = 0; j < 8; ++j) {
      const int i = tid * 8 + j;
      const float2 xy = *reinterpret_cast<const float2*>(P + (size_t)i * 6);
      const float z = P[i * 6 + 2];
      v4f c4;
      c4.x = xy.x; c4.y = xy.y; c4.z = z; c4.w = 0.0f;
      *reinterpret_cast<v4f*>(&u.f.cache[i * 4]) = c4;
    }
    if (tid < RING * FPS_W) u.f.wtag[tid >> 3][tid & 7] = 0;  // tags below any k
    __syncthreads();  // cache + tag init ready (all 16 waves present)

    if (wave == FPS_W) {
      // ===== publisher wave: consumes the slot ring, owns C + prog =====
      if (lane == 0) {  // C[0] = start point (index 0, reference semantics)
        C[0] = u.f.cache[0];
        C[1] = u.f.cache[1];
        C[2] = u.f.cache[2];
      }
      for (int k = 1; k < NGRP; ++k) {
        // publish BEFORE storing C[k]: at this point C[0..k-1] are issued in
        // program order -> the release (waitcnt + wbl2) covers exactly them.
        if ((k & 7) == 0 && lane == 0)
          __hip_atomic_store(prog, (unsigned)k, __ATOMIC_RELEASE,
                             __HIP_MEMORY_SCOPE_AGENT);
        const int p = k & (RING - 1);
        // sleep-poll: fires only when caught up; parked wave issues nothing
        // -> no SIMD0 issue contention against compute waves 0/4.
        for (;;) {
          const unsigned tg =
              __hip_atomic_load(&u.f.wtag[p][lane & 7], __ATOMIC_ACQUIRE,
                                __HIP_MEMORY_SCOPE_WORKGROUP);
          if (__ballot(tg == (unsigned)k) == ~0ull) break;
          __builtin_amdgcn_s_sleep(1);
        }

        const v4f sl =
            *reinterpret_cast<const v4f*>(&u.f.wdata[p][lane & 7][0]);
        float r = sl.x;
        r = dpp_max_f32<0x111>(r); r = dpp_max_f32<0x112>(r);
        r = dpp_max_f32<0x114>(r);
        const float gmax =
            __int_as_float(__builtin_amdgcn_readlane(__float_as_int(r), 7));
        const int sstar =
            (int)__builtin_ctzll(__ballot(sl.x == gmax) & 0xFFull);
        const float lx =
            __int_as_float(__builtin_amdgcn_readlane(__float_as_int(sl.y), sstar));
        const float ly =
            __int_as_float(__builtin_amdgcn_readlane(__float_as_int(sl.z), sstar));
        const float lz =
            __int_as_float(__builtin_amdgcn_readlane(__float_as_int(sl.w), sstar));
        if (lane == 0) {
          C[k * 3 + 0] = lx;
          C[k * 3 + 1] = ly;
          C[k * 3 + 2] = lz;
        }
      }
      if (lane == 0)  // final full publish (release drains all C stores)
        __hip_atomic_store(prog, (unsigned)NGRP, __ATOMIC_RELEASE,
                           __HIP_MEMORY_SCOPE_AGENT);
      return;
    }
    if (tid >= FPS_TPB) return;  // waves 9..15 retire; no barriers after this

    // register preload from LDS cache: 16 contiguous points per thread
    v2f px[8], py[8], pz[8], md[8];
#pragma unroll
    for (int m = 0; m < 8; ++m) {
      const v4f a =
          *reinterpret_cast<const v4f*>(&u.f.cache[(tid * FPS_PPT + 2 * m) * 4]);
      const v4f bb = *reinterpret_cast<const v4f*>(
          &u.f.cache[(tid * FPS_PPT + 2 * m + 1) * 4]);
      px[m] = (v2f){a.x, bb.x};
      py[m] = (v2f){a.y, bb.y};
      pz[m] = (v2f){a.z, bb.z};
      md[m] = (v2f){__builtin_inff(), __builtin_inff()};
    }
    float lx, ly, lz;
    {
      const v4f c0 = *reinterpret_cast<const v4f*>(&u.f.cache[0]);
      lx = c0.x; ly = c0.y; lz = c0.z;  // start index 0 (reference)
    }

    for (int k = 1; k < NGRP; ++k) {
      // ---- inner: packed min-dist update + per-thread max ----
      const v2f vlx = {lx, lx}, vly = {ly, ly}, vlz = {lz, lz};
      v2f b2 = {-__builtin_inff(), -__builtin_inff()};
#pragma unroll
      for (int m = 0; m < 8; ++m) {
        const v2f dx = px[m] - vlx;
        const v2f dy = py[m] - vly;
        const v2f dz = pz[m] - vlz;
        const v2f d  = (dx * dx + dy * dy) + dz * dz;  // ref op order, no fma
        md[m] = __builtin_elementwise_min(md[m], d);
        b2 = __builtin_elementwise_max(b2, md[m]);
      }
      const float bestv = fmaxf(b2.x, b2.y);

      // first (min) index attaining bestv: cmp/sel + min-tree (depth 3).
      // .x (2m) overrides .y (2m+1); min over m -> lowest j. Same semantics
      // as the r17 descending-scan.
      unsigned cnd[8];
#pragma unroll
      for (int m = 0; m < 8; ++m) {
        unsigned cm = (md[m].y == bestv) ? (unsigned)(2 * m + 1) : 0xFFFFFFFFu;
        cm = (md[m].x == bestv) ? (unsigned)(2 * m) : cm;
        cnd[m] = cm;
      }
      const unsigned m01 = cnd[0] < cnd[1] ? cnd[0] : cnd[1];
      const unsigned m23 = cnd[2] < cnd[3] ? cnd[2] : cnd[3];
      const unsigned m45 = cnd[4] < cnd[5] ? cnd[4] : cnd[5];
      const unsigned m67 = cnd[6] < cnd[7] ? cnd[6] : cnd[7];
      const unsigned m03 = m01 < m23 ? m01 : m23;
      const unsigned m47 = m45 < m67 ? m45 : m67;
      const unsigned cmin = m03 < m47 ? m03 : m47;
      const unsigned idxbest = (unsigned)tid * FPS_PPT + cmin;

      // speculative own-candidate coord fetch: issued BEFORE the DPP chain,
      // waitcnt lands in the owner branch -> latency hidden under the reduce.
      const v4f cg =
          *reinterpret_cast<const v4f*>(&u.f.cache[idxbest * 4]);

      // ---- level-1: wave max via DPP (VALU only) ----
      float wv = bestv;
      wv = dpp_max_f32<0x111>(wv); wv = dpp_max_f32<0x112>(wv);
      wv = dpp_max_f32<0x114>(wv); wv = dpp_max_f32<0x118>(wv);
      wv = dpp_max_f32<0x142>(wv); wv = dpp_max_f32<0x143>(wv);
      const float wvmax =
          __int_as_float(__builtin_amdgcn_readlane(__float_as_int(wv), 63));
      const int owner = (int)__builtin_ctzll(__ballot(bestv == wvmax));

      const int p = k & (RING - 1);
      if (lane == owner) {
        v4f s;
        s.x = wvmax; s.y = cg.x; s.z = cg.y; s.w = cg.z;
        *reinterpret_cast<v4f*>(&u.f.wdata[p][wave][0]) = s;  // one b128
        __hip_atomic_store(&u.f.wtag[p][wave], (unsigned)k, __ATOMIC_RELEASE,
                           __HIP_MEMORY_SCOPE_WORKGROUP);
      }

      // ---- tag poll replaces __syncthreads (no vmcnt drain) ----
      unsigned tg;
      do {
        tg = __hip_atomic_load(&u.f.wtag[p][lane & 7], __ATOMIC_ACQUIRE,
                               __HIP_MEMORY_SCOPE_WORKGROUP);
      } while (__ballot(tg == (unsigned)k) != ~0ull);

      // ---- level-2: ONE b128 slot read, 3-step DPP, coord readlanes ----
      const v4f sl =
          *reinterpret_cast<const v4f*>(&u.f.wdata[p][lane & 7][0]);
      float r = sl.x;
      r = dpp_max_f32<0x111>(r); r = dpp_max_f32<0x112>(r);
      r = dpp_max_f32<0x114>(r);
      const float gmax =
          __int_as_float(__builtin_amdgcn_readlane(__float_as_int(r), 7));
      const int sstar =
          (int)__builtin_ctzll(__ballot(sl.x == gmax) & 0xFFull);
      lx = __int_as_float(__builtin_amdgcn_readlane(__float_as_int(sl.y), sstar));
      ly = __int_as_float(__builtin_amdgcn_readlane(__float_as_int(sl.z), sstar));
      lz = __int_as_float(__builtin_amdgcn_readlane(__float_as_int(sl.w), sstar));
    }
    // compute waves: nothing to finalize -- publisher owns C[511] + prog.
  } else {
    // ====== kNN role: 4 groups per block (tie-fast-path) ========
    const unsigned gid = ticket - BATCH;           // g-major ordering
    const int b  = (int)(gid & 15);
    const int g0 = (int)(gid >> 4) * GPB;
    const int sub  = tid >> 8;                     // subunit 0..3
    const int t256 = tid & 255;                    // tid within subunit
    const int g = g0 + sub;
    const float* P = points + (size_t)b * NPTS * NCH;
    const float* cen = centers + ((size_t)b * NGRP + g) * 3;
    unsigned* prog = ws + 32 + b * 32;

    if (tid == 0) {  // spin until all 4 centers are published
      while (__hip_atomic_load(prog, __ATOMIC_ACQUIRE,
                               __HIP_MEMORY_SCOPE_AGENT) <
             (unsigned)(g0 + GPB))
        __builtin_amdgcn_s_sleep(64);
    }
    __syncthreads();

    // center via agent-scope atomic loads (fresh across XCDs)
    const float cx = __hip_atomic_load(&cen[0], __ATOMIC_RELAXED,
                                       __HIP_MEMORY_SCOPE_AGENT);
    const float cy = __hip_atomic_load(&cen[1], __ATOMIC_RELAXED,
                                       __HIP_MEMORY_SCOPE_AGENT);
    const float cz = __hip_atomic_load(&cen[2], __ATOMIC_RELAXED,
                                       __HIP_MEMORY_SCOPE_AGENT);
    const float cc = (cx * cx + cy * cy) + cz * cz;

    unsigned long long keys[32];
#pragma unroll
    for (int j = 0; j < 32; ++j) {
      const int i = j * 256 + t256;
      const float2 xy = *reinterpret_cast<const float2*>(P + (size_t)i * 6);
      const float x = xy.x, y = xy.y;
      const float z = P[i * 6 + 2];
      const float xx  = (x * x + y * y) + z * z;
      const float dot = fmaf(cz, z, fmaf(cy, y, cx * x));  // einsum fma chain
      const float d2  = (cc - 2.0f * dot) + xx;
      unsigned uu = __float_as_uint(d2);
      uu = (uu & 0x80000000u) ? ~uu : (uu | 0x80000000u);  // sortable map
      keys[j] = ((unsigned long long)uu << 32) | (unsigned long long)(unsigned)i;
    }

    // 4 group mins (8 keys each) + overall min
    unsigned long long gm[4];
#pragma unroll
    for (int g2 = 0; g2 < 4; ++g2) {
      unsigned long long m = keys[g2 * 8];
#pragma unroll
      for (int t = 1; t < 8; ++t) {
        const unsigned long long o = keys[g2 * 8 + t];
        m = m < o ? m : o;
      }
      gm[g2] = m;
    }
    unsigned long long lmin;
    {
      const unsigned long long a2 = gm[0] < gm[1] ? gm[0] : gm[1];
      const unsigned long long b3 = gm[2] < gm[3] ? gm[2] : gm[3];
      lmin = a2 < b3 ? a2 : b3;
    }

    // ---- phase 1: per-wave top-32, NO barriers; tie-fast-path rounds ----
    for (int r2 = 0; r2 < GSZ; ++r2) {
      const unsigned vcur = (unsigned)(lmin >> 32);
      const unsigned icur = (unsigned)(lmin & 0xFFFFFFFFull);
      unsigned vm = vcur;
      vm = dpp_min_u32<0x111>(vm); vm = dpp_min_u32<0x112>(vm);
      vm = dpp_min_u32<0x114>(vm); vm = dpp_min_u32<0x118>(vm);
      vm = dpp_min_u32<0x142>(vm); vm = dpp_min_u32<0x143>(vm);
      const unsigned vmin = (unsigned)__builtin_amdgcn_readlane((int)vm, 63);

      // fast path: unique lane holds vmin -> its icur is the exact
      // (val,idx)-lexicographic min index. Fallback (bit-identical cross-
      // lane val tie, rare): full idx DPP chain, identical to r10-r16.
      const unsigned long long mask = __ballot(vcur == vmin);
      unsigned imin;
      if (__builtin_popcountll(mask) == 1) {  // wave-uniform branch
        imin = (unsigned)__builtin_amdgcn_readlane(
            (int)icur, (int)__builtin_ctzll(mask));
      } else {
        unsigned ic = (vcur == vmin) ? icur : 0xFFFFFFFFu;
        ic = dpp_min_u32<0x111>(ic); ic = dpp_min_u32<0x112>(ic);
        ic = dpp_min_u32<0x114>(ic); ic = dpp_min_u32<0x118>(ic);
        ic = dpp_min_u32<0x142>(ic); ic = dpp_min_u32<0x143>(ic);
        imin = (unsigned)__builtin_amdgcn_readlane((int)ic, 63);
      }
      const unsigned long long wk =
          ((unsigned long long)vmin << 32) | (unsigned long long)imin;

      if (lane == (int)(imin & 63u)) {  // owner removes winner
#pragma unroll
        for (int g2 = 0; g2 < 4; ++g2) {
          if (gm[g2] == wk) {
            unsigned long long m = ~0ull;
#pragma unroll
            for (int t = 0; t < 8; ++t) {
              const int s = g2 * 8 + t;
              if (keys[s] == wk) keys[s] = ~0ull;
              const unsigned long long o = keys[s];
              m = m < o ? m : o;
            }
            gm[g2] = m;
          }
        }
        const unsigned long long a2 = gm[0] < gm[1] ? gm[0] : gm[1];
        const unsigned long long b3 = gm[2] < gm[3] ? gm[2] : gm[3];
        lmin = a2 < b3 ? a2 : b3;
      }
      if (lane == 0) u.k.wtop[wave][r2] = wk;
    }
    __syncthreads();  // wtop ready

    // ---- phase 2: wave 4*sub bitonic-sorts its 128 candidates ----
    if ((wave & 3) == 0) {
      const unsigned long long* flat = &u.k.wtop[4 * sub][0];
      unsigned long long a = flat[lane];
      unsigned long long c = flat[lane + 64];
#pragma unroll
      for (int k2 = 2; k2 <= 128; k2 <<= 1) {
#pragma unroll
        for (int j2 = k2 >> 1; j2 >= 1; j2 >>= 1) {
          if (j2 == 64) {  // within-lane slot exchange (only at k2 == 128)
            const unsigned long long mn = a < c ? a : c;
            const unsigned long long mx = a < c ? c : a;
            a = mn; c = mx;
          } else {
            const bool upa = ((lane & k2) == 0);
            const bool upc = (((lane + 64) & k2) == 0);
            const unsigned long long oa = __shfl_xor(a, j2);
            const unsigned long long oc = __shfl_xor(c, j2);
            const bool low = ((lane & j2) == 0);
            const unsigned long long mna = a < oa ? a : oa;
            const unsigned long long mxa = a < oa ? oa : a;
            const unsigned long long mnc = c < oc ? c : oc;
            const unsigned long long mxc = c < oc ? oc : c;
            a = (low == upa) ? mna : mxa;
            c = (low == upc) ? mnc : mxc;
          }
        }
      }
      if (lane < GSZ) u.k.knn_sh[sub][lane] = (int)(unsigned)(a & 0xFFFFFFFFull);
    }
    __syncthreads();

    // gather + center-relative xyz; 192 output floats per group
    float* outg = grouped + ((size_t)b * NGRP + g) * GSZ * NCH;
    if (t256 < GSZ * NCH) {
      const int n = t256 / 6, c2 = t256 % 6;
      const int idx = u.k.knn_sh[sub][n];
      float v = P[idx * 6 + c2];
      if (c2 < 3) {
        const float cv = (c2 == 0) ? cx : (c2 == 1) ? cy : cz;
        v = v - cv;  // exact ref subtract
      }
      outg[t256] = v;
    }
  }
}

extern "C" void kernel_launch(void* const* d_in, const int* in_sizes, int n_in,
                              void* d_out, int out_size, void* d_ws, size_t ws_size,
                              hipStream_t stream) {
  const float* points = (const float*)d_in[0];
  float* out = (float*)d_out;
  float* grouped = out;                                        // [16,512,32,6]
  float* centers = out + (size_t)BATCH * NGRP * GSZ * NCH;     // [16,512,3]
  unsigned* ws = (unsigned*)d_ws;

  // zero ticket counter + progress flags (ws is poisoned 0xAA pre-launch)
  hipMemsetAsync(ws, 0, 4096, stream);
  fused_kernel<<<BATCH + KNB, TPB, 0, stream>>>(points, grouped, centers, ws);
}